// Round 8
// baseline (150.694 us; speedup 1.0000x reference)
//
#include <hip/hip_runtime.h>

#define HW   6144
#define WID  96
#define HEI  64
#define IC   243

// half-unit offsets in ws
#define HF1   0u
#define HL0   1572864u
#define HL1   3145728u
#define HL2   3538944u
#define WTH   3637248u
// float-unit offsets (half region ends at half idx 3670016 = float 1835008)
#define FYP   1835008u
#define FST   3407872u
#define FST2  3408128u

typedef _Float16 h8 __attribute__((ext_vector_type(8)));
typedef float f32x4 __attribute__((ext_vector_type(4)));

// LDS-tiled transpose [B,C,HW] f32 -> [pix][ch] fp16. grid (192, 4, 2)
__global__ void k_t(const float* __restrict__ f1, const float* __restrict__ f2,
                    float* __restrict__ ws) {
    _Float16* wh = (_Float16*)ws;
    const float* src = blockIdx.z ? f2 : f1;
    _Float16* dst = wh + (blockIdx.z ? HL0 : HF1);
    const int t = threadIdx.x;
    const int pix0 = blockIdx.x * 64;
    const int c0 = blockIdx.y * 32;
    const int b = pix0 / HW;
    const int pb = pix0 - b * HW;
    __shared__ float sT[32][65];
    const int px = t & 63;
    const int cb8 = (t >> 6) * 8;
    #pragma unroll
    for (int i = 0; i < 8; i++)
        sT[cb8 + i][px] = src[((size_t)(b * 128 + c0 + cb8 + i)) * HW + pb + px];
    __syncthreads();
    const int pw = t >> 2;
    const int cg = (t & 3) * 8;
    h8 hv;
    #pragma unroll
    for (int i = 0; i < 8; i++) hv[i] = (_Float16)sT[cg + i][pw];
    *(h8*)(dst + ((size_t)(pix0 + pw)) * 128 + c0 + cg) = hv;
}

// conv weights -> fp16 [o][k] padded to 256. grid 128
__global__ void k_wt(const float* __restrict__ w, float* __restrict__ ws) {
    _Float16* wth = (_Float16*)ws + WTH;
    int tid = blockIdx.x * 256 + threadIdx.x;   // 0..32767
    int o = tid >> 8, k = tid & 255;
    wth[tid] = (k < IC) ? (_Float16)w[o * IC + k] : (_Float16)0.f;
}

// fp16 2x2 avg-pool, channel-last
__global__ void k_pool(const _Float16* __restrict__ src, _Float16* __restrict__ dst,
                       int Ho, int Wo) {
    int gt = blockIdx.x * 256 + threadIdx.x;
    int oc = gt & 15;
    int rest = gt >> 4;
    int x = rest % Wo; rest /= Wo;
    int y = rest % Ho; int b = rest / Ho;
    int Wi = Wo * 2;
    const _Float16* s = src + ((size_t)((b * (Ho * 2) + 2 * y) * Wi + 2 * x)) * 128 + oc * 8;
    h8 a  = *(const h8*)s;
    h8 bb = *(const h8*)(s + 128);
    h8 c  = *(const h8*)(s + (size_t)Wi * 128);
    h8 d  = *(const h8*)(s + (size_t)Wi * 128 + 128);
    h8 r;
    #pragma unroll
    for (int j = 0; j < 8; j++)
        r[j] = (_Float16)(0.25f * ((float)a[j] + (float)bb[j] + (float)c[j] + (float)d[j]));
    *(h8*)(dst + (size_t)gt * 8) = r;
}

// Fused: MFMA-diagonal corr taps + bilinear + MFMA 1x1 conv.
// 256 thr, 16 px/block, grid 768. Wave wv handles taps t = wv + 4j, j in [0,75).
__launch_bounds__(256)
__global__ void k_corr_conv(const float* __restrict__ txy, const float* __restrict__ cb,
                            float* __restrict__ ws) {
    const _Float16* wh = (const _Float16*)ws;
    const int tid = threadIdx.x;
    const int pix0 = blockIdx.x * 16;
    const int b = pix0 / HW;
    const int pb0 = pix0 - b * HW;

    __shared__ _Float16 sGh[16 * 300];   // [p][t]
    __shared__ _Float16 sFh[16 * 256];   // [p][k] XOR-swizzled in 16B units
    __shared__ float sLev[16 * 12];

    if (tid < 48) {
        int p = tid / 3, lev = tid - 3 * p;
        float tx = txy[(b * 2 + 0) * HW + pb0 + p];
        float ty = txy[(b * 2 + 1) * HW + pb0 + p];
        float inv = (lev == 0) ? 1.f : ((lev == 1) ? 0.5f : 0.25f);
        float xs = tx * inv, ys = ty * inv;
        float X0 = floorf(xs), Y0 = floorf(ys);
        sLev[p * 12 + lev * 4 + 0] = X0;
        sLev[p * 12 + lev * 4 + 1] = Y0;
        sLev[p * 12 + lev * 4 + 2] = xs - X0;
        sLev[p * 12 + lev * 4 + 3] = ys - Y0;
    }
    if (tid < 208) {   // zero sFh pad k in [243,256)
        int p = tid / 13, k = 243 + tid - (tid / 13) * 13;
        int kb = k >> 3, ke = k & 7;
        sFh[p * 256 + ((kb ^ (p & 7)) << 3) + ke] = (_Float16)0.f;
    }

    const int l = tid & 63;
    const int wv = __builtin_amdgcn_readfirstlane(tid >> 6);
    const int p = l & 15;
    const int kq = l >> 4;                  // k-block 0..3
    const bool diag = (kq == (p >> 2));
    const int sel = p & 3;

    // A fragments: f1 for the 16 pixels, K=128 in 4 steps
    const _Float16* f1p = wh + HF1 + ((size_t)(pix0 + p)) * 128 + kq * 8;
    const h8 av0 = *(const h8*)(f1p);
    const h8 av1 = *(const h8*)(f1p + 32);
    const h8 av2 = *(const h8*)(f1p + 64);
    const h8 av3 = *(const h8*)(f1p + 96);

    __syncthreads();

    const float scale = 0.08838834764831845f;   // 1/sqrt(128)

    #pragma unroll
    for (int lev = 0; lev < 3; ++lev) {
        const int WL = WID >> lev, HL = HEI >> lev;
        const _Float16* f2b = wh + ((lev == 0) ? HL0 : ((lev == 1) ? HL1 : HL2))
                              + (size_t)b * HL * WL * 128 + kq * 8;
        const int X0 = (int)sLev[p * 12 + lev * 4 + 0];
        const int Y0 = (int)sLev[p * 12 + lev * 4 + 1];

        h8 A0, A1, A2, A3, B0, B1, B2, B3;
        bool okA, okB; int tA, tB;

        auto issue = [&](int j, h8& v0, h8& v1, h8& v2, h8& v3, bool& okf, int& ts) {
            int t = wv + 4 * j;
            int tl = t - lev * 100;
            int r = tl / 10, c = tl - 10 * r;      // wave-uniform
            int y = Y0 - 4 + r, x = X0 - 4 + c;
            okf = ((unsigned)x < (unsigned)WL) && ((unsigned)y < (unsigned)HL);
            int xc = min(max(x, 0), WL - 1), yc = min(max(y, 0), HL - 1);
            const _Float16* cp = f2b + ((size_t)(yc * WL + xc)) * 128;
            v0 = *(const h8*)cp;
            v1 = *(const h8*)(cp + 32);
            v2 = *(const h8*)(cp + 64);
            v3 = *(const h8*)(cp + 96);
            ts = t;
        };
        auto compute = [&](h8 v0, h8 v1, h8 v2, h8 v3, bool okf, int t) {
            f32x4 acc = {0.f, 0.f, 0.f, 0.f};
            acc = __builtin_amdgcn_mfma_f32_16x16x32_f16(av0, v0, acc, 0, 0, 0);
            acc = __builtin_amdgcn_mfma_f32_16x16x32_f16(av1, v1, acc, 0, 0, 0);
            acc = __builtin_amdgcn_mfma_f32_16x16x32_f16(av2, v2, acc, 0, 0, 0);
            acc = __builtin_amdgcn_mfma_f32_16x16x32_f16(av3, v3, acc, 0, 0, 0);
            if (diag) {
                float v = (sel == 0) ? acc[0] : (sel == 1) ? acc[1] : (sel == 2) ? acc[2] : acc[3];
                sGh[p * 300 + t] = okf ? (_Float16)(v * scale) : (_Float16)0.f;
            }
        };

        const int j0 = lev * 25, jend = j0 + 25;
        int j = j0;
        issue(j, A0, A1, A2, A3, okA, tA);
        while (true) {
            bool haveB = (j + 1 < jend);
            if (haveB) issue(j + 1, B0, B1, B2, B3, okB, tB);
            compute(A0, A1, A2, A3, okA, tA);
            ++j;
            if (!haveB) break;
            bool haveA = (j + 1 < jend);
            if (haveA) issue(j + 1, A0, A1, A2, A3, okA, tA);
            compute(B0, B1, B2, B3, okB, tB);
            ++j;
            if (!haveA) break;
        }
    }
    __syncthreads();

    // bilinear combine -> sFh[p][k] fp16 (swizzled)
    for (int idx = tid; idx < 16 * IC; idx += 256) {
        int k = idx >> 4, p2 = idx & 15;
        int lev = (k < 81) ? 0 : ((k < 162) ? 1 : 2);
        int kk = k - lev * 81;
        int dyi = (kk * 57) >> 9, dxi = kk - 9 * dyi;
        float fx = sLev[p2 * 12 + lev * 4 + 2];
        float fy = sLev[p2 * 12 + lev * 4 + 3];
        const _Float16* Gp = sGh + p2 * 300 + lev * 100 + dyi * 10 + dxi;
        float v = (1.f - fy) * ((1.f - fx) * (float)Gp[0] + fx * (float)Gp[1])
                +        fy  * ((1.f - fx) * (float)Gp[10] + fx * (float)Gp[11]);
        int kb = k >> 3, ke = k & 7;
        sFh[p2 * 256 + ((kb ^ (p2 & 7)) << 3) + ke] = (_Float16)v;
    }
    __syncthreads();

    // 1x1 conv via MFMA: wave wv does out-tiles om = wv and wv+4
    const _Float16* wth = wh + WTH;
    const int om0 = wv, om1 = wv + 4;
    const _Float16* wtb0 = wth + (om0 * 16 + p) * 256 + kq * 8;
    const _Float16* wtb1 = wth + (om1 * 16 + p) * 256 + kq * 8;
    f32x4 acc0 = {0.f, 0.f, 0.f, 0.f}, acc1 = {0.f, 0.f, 0.f, 0.f};
    #pragma unroll
    for (int s = 0; s < 8; ++s) {
        int kb = s * 4 + kq;
        h8 bv = *(const h8*)(sFh + p * 256 + ((kb ^ (p & 7)) << 3));
        h8 a0 = *(const h8*)(wtb0 + s * 32);
        h8 a1 = *(const h8*)(wtb1 + s * 32);
        acc0 = __builtin_amdgcn_mfma_f32_16x16x32_f16(a0, bv, acc0, 0, 0, 0);
        acc1 = __builtin_amdgcn_mfma_f32_16x16x32_f16(a1, bv, acc1, 0, 0, 0);
    }
    const int row4 = kq * 4;
    float4 bb0 = *(const float4*)&cb[om0 * 16 + row4];
    float4 bb1 = *(const float4*)&cb[om1 * 16 + row4];
    float* op0 = ws + FYP + ((size_t)(pix0 + p)) * 128 + om0 * 16 + row4;
    float* op1 = ws + FYP + ((size_t)(pix0 + p)) * 128 + om1 * 16 + row4;
    op0[0] = acc0[0] + bb0.x; op0[1] = acc0[1] + bb0.y;
    op0[2] = acc0[2] + bb0.z; op0[3] = acc0[3] + bb0.w;
    op1[0] = acc1[0] + bb1.x; op1[1] = acc1[1] + bb1.y;
    op1[2] = acc1[2] + bb1.z; op1[3] = acc1[3] + bb1.w;
}

__global__ void k_gnpart(float* __restrict__ ws) {
    const int s = blockIdx.x;     // slice 0..7
    const int bg = blockIdx.y;    // 0..15
    const int b = bg >> 3, g = bg & 7;
    const int tid = threadIdx.x;
    const float* yp = ws + FYP + (size_t)b * HW * 128 + g * 16;
    float sum = 0.f, sum2 = 0.f;
    for (int idx = tid; idx < 768 * 16; idx += 256) {
        int pix = s * 768 + (idx >> 4);
        float v = yp[(size_t)pix * 128 + (idx & 15)];
        sum += v; sum2 += v * v;
    }
    __shared__ float rs[256], rs2[256];
    rs[tid] = sum; rs2[tid] = sum2;
    __syncthreads();
    for (int st = 128; st > 0; st >>= 1) {
        if (tid < st) { rs[tid] += rs[tid + st]; rs2[tid] += rs2[tid + st]; }
        __syncthreads();
    }
    if (tid == 0) {
        ws[FST + (bg * 8 + s) * 2]     = rs[0];
        ws[FST + (bg * 8 + s) * 2 + 1] = rs2[0];
    }
}

__global__ void k_gnfinal(float* __restrict__ ws) {
    int t = threadIdx.x;
    if (t < 16) {
        float s = 0.f, s2 = 0.f;
        for (int i = 0; i < 8; i++) {
            s  += ws[FST + (t * 8 + i) * 2];
            s2 += ws[FST + (t * 8 + i) * 2 + 1];
        }
        const float invN = 1.f / (float)(HW * 16);
        float mean = s * invN;
        float var = s2 * invN - mean * mean;
        ws[FST2 + t * 2]     = mean;
        ws[FST2 + t * 2 + 1] = rsqrtf(var + 1e-5f);
    }
}

__global__ void k_finish(const float* __restrict__ gw, const float* __restrict__ gb,
                         const float* __restrict__ ws, float* __restrict__ out) {
    int tid = blockIdx.x * 256 + threadIdx.x;   // [b][c][pix], pix fastest
    int pix = tid % HW;
    int c = (tid / HW) & 127;
    int b = tid / (HW * 128);
    int g = c >> 4;
    float mean = ws[FST2 + (b * 8 + g) * 2];
    float rstd = ws[FST2 + (b * 8 + g) * 2 + 1];
    float v = ws[FYP + ((size_t)(b * HW + pix)) * 128 + c];
    v = (v - mean) * rstd * gw[c] + gb[c];
    out[tid] = v > 0.f ? v : 0.1f * v;
}

extern "C" void kernel_launch(void* const* d_in, const int* in_sizes, int n_in,
                              void* d_out, int out_size, void* d_ws, size_t ws_size,
                              hipStream_t stream) {
    const float* f1  = (const float*)d_in[0];
    const float* f2  = (const float*)d_in[1];
    const float* txy = (const float*)d_in[2];
    const float* cw  = (const float*)d_in[3];
    const float* cb  = (const float*)d_in[4];
    const float* gw  = (const float*)d_in[5];
    const float* gb  = (const float*)d_in[6];
    float* ws = (float*)d_ws;
    _Float16* whp = (_Float16*)d_ws;
    float* out = (float*)d_out;

    k_t<<<dim3(192, 4, 2), 256, 0, stream>>>(f1, f2, ws);
    k_wt<<<128, 256, 0, stream>>>(cw, ws);
    k_pool<<<192, 256, 0, stream>>>(whp + HL0, whp + HL1, 32, 48);
    k_pool<<<48, 256, 0, stream>>>(whp + HL1, whp + HL2, 16, 24);
    k_corr_conv<<<768, 256, 0, stream>>>(txy, cb, ws);
    k_gnpart<<<dim3(8, 16), 256, 0, stream>>>(ws);
    k_gnfinal<<<1, 64, 0, stream>>>(ws);
    k_finish<<<6144, 256, 0, stream>>>(gw, gb, ws, out);
}